// Round 1
// baseline (2647.196 us; speedup 1.0000x reference)
//
#include <hip/hip_runtime.h>
#include <math.h>

#define Bsz  4
#define Tlen 2048
#define Dm   1024
#define Hh   8
#define dh   128
#define Mrows (Bsz * Tlen)   // 8192

// ---------------------------------------------------------------------------
// GEMM: Y[m][n] = sum_k A[m][k] * W[n][k]  (+ bias[n] if bias != nullptr)
// A: Mrows x 1024 row-major; W: 1024 x 1024 row-major (torch Linear weight)
// Tile 64x64, BK=16, 256 threads, 4x4 per thread. fp32 (no MFMA for fp32).
// ---------------------------------------------------------------------------
#define BM 64
#define BN 64
#define BK 16

__global__ __launch_bounds__(256) void gemm_bt(const float* __restrict__ A,
                                               const float* __restrict__ W,
                                               const float* __restrict__ bias,
                                               float* __restrict__ Y)
{
    __shared__ __align__(16) float As[BK][BM];
    __shared__ __align__(16) float Bs[BK][BN];

    const int t  = threadIdx.x;
    const int tx = t & 15;          // n sub-tile
    const int ty = t >> 4;          // m sub-tile
    const int m0 = blockIdx.y * BM;
    const int n0 = blockIdx.x * BN;

    const int lr = t >> 2;          // 0..63: row within tile for staging
    const int lc = (t & 3) << 2;    // 0,4,8,12: k offset for staging (float4)

    float c[4][4] = {{0.f}};

    const float* Arow = A + (size_t)(m0 + lr) * Dm + lc;
    const float* Wrow = W + (size_t)(n0 + lr) * Dm + lc;

    for (int k0 = 0; k0 < Dm; k0 += BK) {
        const float4 av = *(const float4*)(Arow + k0);
        const float4 bv = *(const float4*)(Wrow + k0);
        __syncthreads();   // protect previous iteration's LDS reads
        As[lc + 0][lr] = av.x; As[lc + 1][lr] = av.y;
        As[lc + 2][lr] = av.z; As[lc + 3][lr] = av.w;
        Bs[lc + 0][lr] = bv.x; Bs[lc + 1][lr] = bv.y;
        Bs[lc + 2][lr] = bv.z; Bs[lc + 3][lr] = bv.w;
        __syncthreads();

#pragma unroll
        for (int kk = 0; kk < BK; ++kk) {
            const float4 a = *(const float4*)&As[kk][ty * 4];
            const float4 b = *(const float4*)&Bs[kk][tx * 4];
            c[0][0] = fmaf(a.x, b.x, c[0][0]); c[0][1] = fmaf(a.x, b.y, c[0][1]);
            c[0][2] = fmaf(a.x, b.z, c[0][2]); c[0][3] = fmaf(a.x, b.w, c[0][3]);
            c[1][0] = fmaf(a.y, b.x, c[1][0]); c[1][1] = fmaf(a.y, b.y, c[1][1]);
            c[1][2] = fmaf(a.y, b.z, c[1][2]); c[1][3] = fmaf(a.y, b.w, c[1][3]);
            c[2][0] = fmaf(a.z, b.x, c[2][0]); c[2][1] = fmaf(a.z, b.y, c[2][1]);
            c[2][2] = fmaf(a.z, b.z, c[2][2]); c[2][3] = fmaf(a.z, b.w, c[2][3]);
            c[3][0] = fmaf(a.w, b.x, c[3][0]); c[3][1] = fmaf(a.w, b.y, c[3][1]);
            c[3][2] = fmaf(a.w, b.z, c[3][2]); c[3][3] = fmaf(a.w, b.w, c[3][3]);
        }
    }

    float4 badd = make_float4(0.f, 0.f, 0.f, 0.f);
    if (bias) badd = *(const float4*)&bias[n0 + tx * 4];
#pragma unroll
    for (int i = 0; i < 4; ++i) {
        const int row = m0 + ty * 4 + i;
        float4 o;
        o.x = c[i][0] + badd.x; o.y = c[i][1] + badd.y;
        o.z = c[i][2] + badd.z; o.w = c[i][3] + badd.w;
        *(float4*)&Y[(size_t)row * Dm + n0 + tx * 4] = o;
    }
}

// ---------------------------------------------------------------------------
// L2-normalize rows of 128 (per b,t,h) for K and V in-place.
// One wave per row, 2 elements per lane.  eps = 1e-12 (torch F.normalize).
// ---------------------------------------------------------------------------
__global__ __launch_bounds__(256) void l2norm_rows(float* __restrict__ Kb,
                                                   float* __restrict__ Vb)
{
    const int gtid = blockIdx.x * 256 + threadIdx.x;
    const int row  = gtid >> 6;            // 0 .. B*T*H-1
    const int lane = threadIdx.x & 63;
    const size_t base = (size_t)row * dh + lane * 2;

    float2 k2 = *(float2*)&Kb[base];
    float2 v2 = *(float2*)&Vb[base];
    float sk = k2.x * k2.x + k2.y * k2.y;
    float sv = v2.x * v2.x + v2.y * v2.y;
#pragma unroll
    for (int off = 1; off < 64; off <<= 1) {
        sk += __shfl_xor(sk, off);
        sv += __shfl_xor(sv, off);
    }
    const float rk = 1.f / fmaxf(sqrtf(sk), 1e-12f);
    const float rv = 1.f / fmaxf(sqrtf(sv), 1e-12f);
    k2.x *= rk; k2.y *= rk;
    v2.x *= rv; v2.y *= rv;
    *(float2*)&Kb[base] = k2;
    *(float2*)&Vb[base] = v2;
}

// ---------------------------------------------------------------------------
// In-place sigmoid (bias already added in GEMM epilogue).
// ---------------------------------------------------------------------------
__global__ __launch_bounds__(256) void sigmoid_k(float* __restrict__ P)
{
    const size_t i = ((size_t)blockIdx.x * 256 + threadIdx.x) * 4;
    float4 v = *(float4*)&P[i];
    v.x = 1.f / (1.f + __expf(-v.x));
    v.y = 1.f / (1.f + __expf(-v.y));
    v.z = 1.f / (1.f + __expf(-v.z));
    v.w = 1.f / (1.f + __expf(-v.w));
    *(float4*)&P[i] = v;
}

// ---------------------------------------------------------------------------
// Delta-rule scan.  State rows are independent:
//   w[i,:] += lr[i]*(v[i] - w[i,:].k) * k ;  o[i] = w[i,:].q
// 1 wave per block; wave = 4 rows x 16 lanes; each lane: 8 cols of w in VGPRs.
// No barriers, k/q prefetched one step ahead.  Grid: B*H*32 = 1024 blocks.
// ---------------------------------------------------------------------------
__global__ __launch_bounds__(64) void scan_kernel(const float* __restrict__ Q,
                                                  const float* __restrict__ Kb,
                                                  const float* __restrict__ Vb,
                                                  const float* __restrict__ LR,
                                                  float* __restrict__ O)
{
    const int bid = blockIdx.x;        // 0..1023
    const int bh  = bid >> 5;          // 0..31
    const int rg  = bid & 31;          // row group 0..31
    const int b   = bh >> 3, h = bh & 7;
    const int lane = threadIdx.x;
    const int rl   = lane >> 4;        // row within group: 0..3
    const int c16  = lane & 15;        // column chunk: 8 cols each
    const int row  = rg * 4 + rl;      // 0..127

    const size_t base = (size_t)b * Tlen * Dm + (size_t)h * dh;
    const float* kp = Kb + base + c16 * 8;
    const float* qp = Q  + base + c16 * 8;
    const float* vp = Vb + base + row;
    const float* lp = LR + base + row;
    float*       op = O  + base + row;

    float w[8] = {0.f, 0.f, 0.f, 0.f, 0.f, 0.f, 0.f, 0.f};

    float4 ka = *(const float4*)(kp);
    float4 kb = *(const float4*)(kp + 4);
    float4 qa = *(const float4*)(qp);
    float4 qb = *(const float4*)(qp + 4);

    for (int t = 0; t < Tlen; ++t) {
        // prefetch t+1 (clamped)
        const size_t offn = (size_t)(t + 1 < Tlen ? t + 1 : t) * Dm;
        const float4 kan = *(const float4*)(kp + offn);
        const float4 kbn = *(const float4*)(kp + offn + 4);
        const float4 qan = *(const float4*)(qp + offn);
        const float4 qbn = *(const float4*)(qp + offn + 4);
        const float vr  = vp[(size_t)t * Dm];
        const float lrr = lp[(size_t)t * Dm];

        // v_old = w . k  (partial over 8 cols, then 16-lane reduce)
        float a0 = fmaf(w[4], kb.x, w[0] * ka.x);
        float a1 = fmaf(w[5], kb.y, w[1] * ka.y);
        float a2 = fmaf(w[6], kb.z, w[2] * ka.z);
        float a3 = fmaf(w[7], kb.w, w[3] * ka.w);
        float vo = (a0 + a1) + (a2 + a3);
        vo += __shfl_xor(vo, 1, 16);
        vo += __shfl_xor(vo, 2, 16);
        vo += __shfl_xor(vo, 4, 16);
        vo += __shfl_xor(vo, 8, 16);

        const float coef = lrr * (vr - vo);
        w[0] = fmaf(coef, ka.x, w[0]); w[1] = fmaf(coef, ka.y, w[1]);
        w[2] = fmaf(coef, ka.z, w[2]); w[3] = fmaf(coef, ka.w, w[3]);
        w[4] = fmaf(coef, kb.x, w[4]); w[5] = fmaf(coef, kb.y, w[5]);
        w[6] = fmaf(coef, kb.z, w[6]); w[7] = fmaf(coef, kb.w, w[7]);

        // o = w_new . q
        float b0 = fmaf(w[4], qb.x, w[0] * qa.x);
        float b1 = fmaf(w[5], qb.y, w[1] * qa.y);
        float b2 = fmaf(w[6], qb.z, w[2] * qa.z);
        float b3 = fmaf(w[7], qb.w, w[3] * qa.w);
        float ov = (b0 + b1) + (b2 + b3);
        ov += __shfl_xor(ov, 1, 16);
        ov += __shfl_xor(ov, 2, 16);
        ov += __shfl_xor(ov, 4, 16);
        ov += __shfl_xor(ov, 8, 16);

        if (c16 == 0) op[(size_t)t * Dm] = ov;

        ka = kan; kb = kbn; qa = qan; qb = qbn;
    }
}

// ---------------------------------------------------------------------------
extern "C" void kernel_launch(void* const* d_in, const int* in_sizes, int n_in,
                              void* d_out, int out_size, void* d_ws, size_t ws_size,
                              hipStream_t stream)
{
    const float* x    = (const float*)d_in[0];
    const float* Wq   = (const float*)d_in[1];
    const float* Wk   = (const float*)d_in[2];
    const float* Wv   = (const float*)d_in[3];
    const float* Wo   = (const float*)d_in[4];
    const float* Wlr  = (const float*)d_in[5];
    const float* b_lr = (const float*)d_in[6];

    float* ws = (float*)d_ws;
    const size_t S = (size_t)Mrows * Dm;   // 8388608 elements
    float* Qb  = ws;
    float* Kb  = ws + S;
    float* Vb  = ws + 2 * S;
    float* LRb = ws + 3 * S;
    float* Ob  = ws + 4 * S;

    dim3 gg(Dm / BN, Mrows / BM);   // (16, 128)
    dim3 gb(256);

    gemm_bt<<<gg, gb, 0, stream>>>(x, Wq, nullptr, Qb);
    gemm_bt<<<gg, gb, 0, stream>>>(x, Wk, nullptr, Kb);
    gemm_bt<<<gg, gb, 0, stream>>>(x, Wv, nullptr, Vb);
    gemm_bt<<<gg, gb, 0, stream>>>(x, Wlr, b_lr, LRb);

    l2norm_rows<<<(Bsz * Tlen * Hh) / 4, 256, 0, stream>>>(Kb, Vb);
    sigmoid_k<<<S / (256 * 4), 256, 0, stream>>>(LRb);

    scan_kernel<<<Bsz * Hh * 32, 64, 0, stream>>>(Qb, Kb, Vb, LRb, Ob);

    gemm_bt<<<gg, gb, 0, stream>>>(Ob, Wo, nullptr, (float*)d_out);
}

// Round 2
// 1166.757 us; speedup vs baseline: 2.2689x; 2.2689x over previous
//
#include <hip/hip_runtime.h>
#include <math.h>

#define Bsz  4
#define Tlen 2048
#define Dm   1024
#define Hh   8
#define dh   128
#define Mrows (Bsz * Tlen)   // 8192

typedef __attribute__((ext_vector_type(8))) short  s16x8;
typedef __attribute__((ext_vector_type(4))) float  f32x4;

// ---------------------------------------------------------------------------
// fp32 -> bf16 (RNE) converter
// ---------------------------------------------------------------------------
__device__ inline unsigned short f2b_rne(float f) {
    unsigned int u = __float_as_uint(f);
    u += 0x7FFFu + ((u >> 16) & 1u);
    return (unsigned short)(u >> 16);
}

__global__ __launch_bounds__(256) void cvt_f32_bf16(const float* __restrict__ in,
                                                    unsigned short* __restrict__ out)
{
    const size_t i = ((size_t)blockIdx.x * 256 + threadIdx.x) * 4;
    float4 v = *(const float4*)&in[i];
    ushort4 o;
    o.x = f2b_rne(v.x); o.y = f2b_rne(v.y);
    o.z = f2b_rne(v.z); o.w = f2b_rne(v.w);
    *(ushort4*)&out[i] = o;
}

// ---------------------------------------------------------------------------
// bf16 MFMA GEMM:  Y[m][n] = sum_k A[m][k]*W[n][k] (+bias[n])
// A: Mrows x 1024 bf16 row-major;  W: 1024 x 1024 bf16 row-major (torch W)
// Block 256 thr = 4 waves; tile 128x128, BK=32; wave = 64x64 = 4x4 MFMAs of
// 16x16x32.  global_load_lds width-16 staging; XOR chunk swizzle for <=2-way
// LDS bank aliasing (free).  C/D map: col=lane&15, row=(lane>>4)*4+reg.
// ---------------------------------------------------------------------------
__global__ __launch_bounds__(256) void gemm_bf16(const unsigned short* __restrict__ A,
                                                 const unsigned short* __restrict__ Wt,
                                                 const float* __restrict__ bias,
                                                 float* __restrict__ Y)
{
    __shared__ __align__(16) unsigned short As[128 * 32];
    __shared__ __align__(16) unsigned short Bs[128 * 32];

    const int tid   = threadIdx.x;
    const int w     = tid >> 6;        // wave 0..3
    const int lane  = tid & 63;
    const int r4    = lane >> 2;       // 0..15 row within 16-row staging call
    const int p4    = lane & 3;        // chunk position 0..3
    const int row16 = lane & 15;
    const int quad  = lane >> 4;       // 0..3

    const int m0 = blockIdx.y * 128;
    const int n0 = blockIdx.x * 128;
    const int wm = (w >> 1) * 64;      // wave sub-tile origin
    const int wn = (w & 1) * 64;

    f32x4 acc[4][4];
#pragma unroll
    for (int i = 0; i < 4; ++i)
#pragma unroll
        for (int j = 0; j < 4; ++j)
            acc[i][j] = (f32x4){0.f, 0.f, 0.f, 0.f};

    for (int k0 = 0; k0 < 1024; k0 += 32) {
        __syncthreads();   // prior iteration's ds_reads done before overwrite
#pragma unroll
        for (int c = 0; c < 2; ++c) {
            const int ml  = w * 32 + c * 16 + r4;       // local row 0..127
            const int swz = (ml >> 1) & 3;
            const unsigned short* ga = A  + (size_t)(m0 + ml) * 1024 + k0 + ((p4 ^ swz) << 3);
            const unsigned short* gb = Wt + (size_t)(n0 + ml) * 1024 + k0 + ((p4 ^ swz) << 3);
            __builtin_amdgcn_global_load_lds(
                (const __attribute__((address_space(1))) void*)ga,
                (__attribute__((address_space(3))) void*)&As[(w * 32 + c * 16) * 32], 16, 0, 0);
            __builtin_amdgcn_global_load_lds(
                (const __attribute__((address_space(1))) void*)gb,
                (__attribute__((address_space(3))) void*)&Bs[(w * 32 + c * 16) * 32], 16, 0, 0);
        }
        __syncthreads();   // drains vmcnt (staging complete)

        s16x8 af[4], bf[4];
#pragma unroll
        for (int bm = 0; bm < 4; ++bm) {
            const int ml  = wm + bm * 16 + row16;
            const int pos = quad ^ ((ml >> 1) & 3);
            af[bm] = *(const s16x8*)&As[ml * 32 + pos * 8];
        }
#pragma unroll
        for (int bn = 0; bn < 4; ++bn) {
            const int nl  = wn + bn * 16 + row16;
            const int pos = quad ^ ((nl >> 1) & 3);
            bf[bn] = *(const s16x8*)&Bs[nl * 32 + pos * 8];
        }
#pragma unroll
        for (int bm = 0; bm < 4; ++bm)
#pragma unroll
            for (int bn = 0; bn < 4; ++bn)
                acc[bm][bn] = __builtin_amdgcn_mfma_f32_16x16x32_bf16(af[bm], bf[bn], acc[bm][bn], 0, 0, 0);
    }

#pragma unroll
    for (int bm = 0; bm < 4; ++bm) {
        const int row = m0 + wm + bm * 16 + quad * 4;
#pragma unroll
        for (int bn = 0; bn < 4; ++bn) {
            const int col = n0 + wn + bn * 16 + row16;
            const float bb = bias ? bias[col] : 0.f;
#pragma unroll
            for (int r = 0; r < 4; ++r)
                Y[(size_t)(row + r) * 1024 + col] = acc[bm][bn][r] + bb;
        }
    }
}

// ---------------------------------------------------------------------------
// L2-normalize rows of 128 (per b,t,h) for K and V in-place.
// ---------------------------------------------------------------------------
__global__ __launch_bounds__(256) void l2norm_rows(float* __restrict__ Kb,
                                                   float* __restrict__ Vb)
{
    const int gtid = blockIdx.x * 256 + threadIdx.x;
    const int row  = gtid >> 6;
    const int lane = threadIdx.x & 63;
    const size_t base = (size_t)row * dh + lane * 2;

    float2 k2 = *(float2*)&Kb[base];
    float2 v2 = *(float2*)&Vb[base];
    float sk = k2.x * k2.x + k2.y * k2.y;
    float sv = v2.x * v2.x + v2.y * v2.y;
#pragma unroll
    for (int off = 1; off < 64; off <<= 1) {
        sk += __shfl_xor(sk, off);
        sv += __shfl_xor(sv, off);
    }
    const float rk = 1.f / fmaxf(sqrtf(sk), 1e-12f);
    const float rv = 1.f / fmaxf(sqrtf(sv), 1e-12f);
    k2.x *= rk; k2.y *= rk;
    v2.x *= rv; v2.y *= rv;
    *(float2*)&Kb[base] = k2;
    *(float2*)&Vb[base] = v2;
}

__global__ __launch_bounds__(256) void sigmoid_k(float* __restrict__ P)
{
    const size_t i = ((size_t)blockIdx.x * 256 + threadIdx.x) * 4;
    float4 v = *(float4*)&P[i];
    v.x = 1.f / (1.f + __expf(-v.x));
    v.y = 1.f / (1.f + __expf(-v.y));
    v.z = 1.f / (1.f + __expf(-v.z));
    v.w = 1.f / (1.f + __expf(-v.w));
    *(float4*)&P[i] = v;
}

// ---------------------------------------------------------------------------
// Delta-rule scan; 1 wave = 4 rows x 16 lanes, 8 state cols per lane.
// Depth-4 register ring prefetch of k/q/v/lr; XCD-aware block swizzle so the
// 32 blocks sharing one (b,h)'s K/Q stream co-locate on one XCD's L2.
// ---------------------------------------------------------------------------
__global__ __launch_bounds__(64) void scan_kernel(const float* __restrict__ Q,
                                                  const float* __restrict__ Kb,
                                                  const float* __restrict__ Vb,
                                                  const float* __restrict__ LR,
                                                  float* __restrict__ O)
{
    const int bid = blockIdx.x;            // 0..1023
    const int xcd = bid & 7;               // assumed XCD round-robin
    const int j   = bid >> 3;              // 0..127
    const int bh  = xcd * 4 + (j & 3);     // 4 (b,h) pairs per XCD
    const int rg  = j >> 2;                // row group 0..31
    const int b   = bh >> 3, h = bh & 7;
    const int lane = threadIdx.x;
    const int rl   = lane >> 4;
    const int c16  = lane & 15;
    const int row  = rg * 4 + rl;

    const size_t base = (size_t)b * Tlen * Dm + (size_t)h * dh;
    const float* kp = Kb + base + c16 * 8;
    const float* qp = Q  + base + c16 * 8;
    const float* vp = Vb + base + row;
    const float* lp = LR + base + row;
    float*       op = O  + base + row;

    float w[8] = {0.f, 0.f, 0.f, 0.f, 0.f, 0.f, 0.f, 0.f};

    float4 kA[4], kB[4], qA[4], qB[4];
    float  vv[4], ll[4];
#pragma unroll
    for (int u = 0; u < 4; ++u) {
        const size_t off = (size_t)u * Dm;
        kA[u] = *(const float4*)(kp + off);
        kB[u] = *(const float4*)(kp + off + 4);
        qA[u] = *(const float4*)(qp + off);
        qB[u] = *(const float4*)(qp + off + 4);
        vv[u] = vp[off];
        ll[u] = lp[off];
    }

    for (int t = 0; t < Tlen; t += 4) {
#pragma unroll
        for (int u = 0; u < 4; ++u) {
            const int tc = t + u;
            const float4 ka = kA[u], kb = kB[u], qa = qA[u], qb = qB[u];
            const float  vr = vv[u], lrr = ll[u];

            // issue prefetch for tc+4 (clamped) before compute
            int tn = tc + 4; if (tn >= Tlen) tn = Tlen - 1;
            const size_t offn = (size_t)tn * Dm;
            kA[u] = *(const float4*)(kp + offn);
            kB[u] = *(const float4*)(kp + offn + 4);
            qA[u] = *(const float4*)(qp + offn);
            qB[u] = *(const float4*)(qp + offn + 4);
            vv[u] = vp[offn];
            ll[u] = lp[offn];

            // v_old = w . k
            float a0 = fmaf(w[4], kb.x, w[0] * ka.x);
            float a1 = fmaf(w[5], kb.y, w[1] * ka.y);
            float a2 = fmaf(w[6], kb.z, w[2] * ka.z);
            float a3 = fmaf(w[7], kb.w, w[3] * ka.w);
            float vo = (a0 + a1) + (a2 + a3);
            vo += __shfl_xor(vo, 1, 16);
            vo += __shfl_xor(vo, 2, 16);
            vo += __shfl_xor(vo, 4, 16);
            vo += __shfl_xor(vo, 8, 16);

            const float coef = lrr * (vr - vo);
            w[0] = fmaf(coef, ka.x, w[0]); w[1] = fmaf(coef, ka.y, w[1]);
            w[2] = fmaf(coef, ka.z, w[2]); w[3] = fmaf(coef, ka.w, w[3]);
            w[4] = fmaf(coef, kb.x, w[4]); w[5] = fmaf(coef, kb.y, w[5]);
            w[6] = fmaf(coef, kb.z, w[6]); w[7] = fmaf(coef, kb.w, w[7]);

            // o = w_new . q
            float b0 = fmaf(w[4], qb.x, w[0] * qa.x);
            float b1 = fmaf(w[5], qb.y, w[1] * qa.y);
            float b2 = fmaf(w[6], qb.z, w[2] * qa.z);
            float b3 = fmaf(w[7], qb.w, w[3] * qa.w);
            float ov = (b0 + b1) + (b2 + b3);
            ov += __shfl_xor(ov, 1, 16);
            ov += __shfl_xor(ov, 2, 16);
            ov += __shfl_xor(ov, 4, 16);
            ov += __shfl_xor(ov, 8, 16);

            if (c16 == 0) op[(size_t)tc * Dm] = ov;
        }
    }
}

// ---------------------------------------------------------------------------
extern "C" void kernel_launch(void* const* d_in, const int* in_sizes, int n_in,
                              void* d_out, int out_size, void* d_ws, size_t ws_size,
                              hipStream_t stream)
{
    const float* x    = (const float*)d_in[0];
    const float* Wq   = (const float*)d_in[1];
    const float* Wk   = (const float*)d_in[2];
    const float* Wv   = (const float*)d_in[3];
    const float* Wo   = (const float*)d_in[4];
    const float* Wlr  = (const float*)d_in[5];
    const float* b_lr = (const float*)d_in[6];

    float* ws = (float*)d_ws;
    const size_t S  = (size_t)Mrows * Dm;    // 8388608
    const size_t SW = (size_t)Dm * Dm;       // 1048576
    float* Qb  = ws;
    float* Kb  = ws + S;
    float* Vb  = ws + 2 * S;
    float* LRb = ws + 3 * S;
    float* Ob  = ws + 4 * S;
    unsigned short* xb  = (unsigned short*)(ws + 5 * S);   // S bf16
    unsigned short* Obb = xb;                              // alias: xb dead before scan ends
    unsigned short* Wqb  = (unsigned short*)(ws + 5 * S + S / 2);
    unsigned short* Wkb  = Wqb + SW;
    unsigned short* Wvb  = Wkb + SW;
    unsigned short* Wlrb = Wvb + SW;
    unsigned short* Wob  = Wlrb + SW;

    // converts
    cvt_f32_bf16<<<S / 1024, 256, 0, stream>>>(x, xb);
    cvt_f32_bf16<<<SW / 1024, 256, 0, stream>>>(Wq, Wqb);
    cvt_f32_bf16<<<SW / 1024, 256, 0, stream>>>(Wk, Wkb);
    cvt_f32_bf16<<<SW / 1024, 256, 0, stream>>>(Wv, Wvb);
    cvt_f32_bf16<<<SW / 1024, 256, 0, stream>>>(Wlr, Wlrb);
    cvt_f32_bf16<<<SW / 1024, 256, 0, stream>>>(Wo, Wob);

    dim3 gg(Dm / 128, Mrows / 128);   // (8, 64)
    gemm_bf16<<<gg, 256, 0, stream>>>(xb, Wqb, nullptr, Qb);
    gemm_bf16<<<gg, 256, 0, stream>>>(xb, Wkb, nullptr, Kb);
    gemm_bf16<<<gg, 256, 0, stream>>>(xb, Wvb, nullptr, Vb);
    gemm_bf16<<<gg, 256, 0, stream>>>(xb, Wlrb, b_lr, LRb);

    l2norm_rows<<<(Bsz * Tlen * Hh) / 4, 256, 0, stream>>>(Kb, Vb);
    sigmoid_k<<<S / 1024, 256, 0, stream>>>(LRb);

    scan_kernel<<<Bsz * Hh * 32, 64, 0, stream>>>(Qb, Kb, Vb, LRb, Ob);

    cvt_f32_bf16<<<S / 1024, 256, 0, stream>>>(Ob, Obb);
    gemm_bf16<<<gg, 256, 0, stream>>>(Obb, Wob, nullptr, (float*)d_out);
}

// Round 3
// 1109.882 us; speedup vs baseline: 2.3851x; 1.0512x over previous
//
#include <hip/hip_runtime.h>
#include <math.h>

#define Bsz  4
#define Tlen 2048
#define Dm   1024
#define Hh   8
#define dh   128
#define Mrows (Bsz * Tlen)   // 8192

typedef __attribute__((ext_vector_type(8))) short  s16x8;
typedef __attribute__((ext_vector_type(4))) float  f32x4;

// ---------------------------------------------------------------------------
// fp32 -> bf16 (RNE)
// ---------------------------------------------------------------------------
__device__ inline unsigned short f2b_rne(float f) {
    unsigned int u = __float_as_uint(f);
    u += 0x7FFFu + ((u >> 16) & 1u);
    return (unsigned short)(u >> 16);
}

__global__ __launch_bounds__(256) void cvt_f32_bf16(const float* __restrict__ in,
                                                    unsigned short* __restrict__ out)
{
    const size_t i = ((size_t)blockIdx.x * 256 + threadIdx.x) * 4;
    float4 v = *(const float4*)&in[i];
    ushort4 o;
    o.x = f2b_rne(v.x); o.y = f2b_rne(v.y);
    o.z = f2b_rne(v.z); o.w = f2b_rne(v.w);
    *(ushort4*)&out[i] = o;
}

// ---------------------------------------------------------------------------
// bf16 MFMA GEMM (m97 recipe): Y[m][n] = sum_k A[m][k]*W[n][k] (+bias[n])
// 128x128 tile, BK=32, 4 waves, 16x16x32 MFMA, global_load_lds w=16,
// XOR chunk swizzle.  C/D map: col=lane&15, row=(lane>>4)*4+reg.
// ---------------------------------------------------------------------------
__global__ __launch_bounds__(256) void gemm_bf16(const unsigned short* __restrict__ A,
                                                 const unsigned short* __restrict__ Wt,
                                                 const float* __restrict__ bias,
                                                 float* __restrict__ Y)
{
    __shared__ __align__(16) unsigned short As[128 * 32];
    __shared__ __align__(16) unsigned short Bs[128 * 32];

    const int tid   = threadIdx.x;
    const int w     = tid >> 6;
    const int lane  = tid & 63;
    const int r4    = lane >> 2;
    const int p4    = lane & 3;
    const int row16 = lane & 15;
    const int quad  = lane >> 4;

    const int m0 = blockIdx.y * 128;
    const int n0 = blockIdx.x * 128;
    const int wm = (w >> 1) * 64;
    const int wn = (w & 1) * 64;

    f32x4 acc[4][4];
#pragma unroll
    for (int i = 0; i < 4; ++i)
#pragma unroll
        for (int j = 0; j < 4; ++j)
            acc[i][j] = (f32x4){0.f, 0.f, 0.f, 0.f};

    for (int k0 = 0; k0 < 1024; k0 += 32) {
        __syncthreads();
#pragma unroll
        for (int c = 0; c < 2; ++c) {
            const int ml  = w * 32 + c * 16 + r4;
            const int swz = (ml >> 1) & 3;
            const unsigned short* ga = A  + (size_t)(m0 + ml) * 1024 + k0 + ((p4 ^ swz) << 3);
            const unsigned short* gb = Wt + (size_t)(n0 + ml) * 1024 + k0 + ((p4 ^ swz) << 3);
            __builtin_amdgcn_global_load_lds(
                (const __attribute__((address_space(1))) void*)ga,
                (__attribute__((address_space(3))) void*)&As[(w * 32 + c * 16) * 32], 16, 0, 0);
            __builtin_amdgcn_global_load_lds(
                (const __attribute__((address_space(1))) void*)gb,
                (__attribute__((address_space(3))) void*)&Bs[(w * 32 + c * 16) * 32], 16, 0, 0);
        }
        __syncthreads();

        s16x8 af[4], bf[4];
#pragma unroll
        for (int bm = 0; bm < 4; ++bm) {
            const int ml  = wm + bm * 16 + row16;
            const int pos = quad ^ ((ml >> 1) & 3);
            af[bm] = *(const s16x8*)&As[ml * 32 + pos * 8];
        }
#pragma unroll
        for (int bn = 0; bn < 4; ++bn) {
            const int nl  = wn + bn * 16 + row16;
            const int pos = quad ^ ((nl >> 1) & 3);
            bf[bn] = *(const s16x8*)&Bs[nl * 32 + pos * 8];
        }
#pragma unroll
        for (int bm = 0; bm < 4; ++bm)
#pragma unroll
            for (int bn = 0; bn < 4; ++bn)
                acc[bm][bn] = __builtin_amdgcn_mfma_f32_16x16x32_bf16(af[bm], bf[bn], acc[bm][bn], 0, 0, 0);
    }

#pragma unroll
    for (int bm = 0; bm < 4; ++bm) {
        const int row = m0 + wm + bm * 16 + quad * 4;
#pragma unroll
        for (int bn = 0; bn < 4; ++bn) {
            const int col = n0 + wn + bn * 16 + row16;
            const float bb = bias ? bias[col] : 0.f;
#pragma unroll
            for (int r = 0; r < 4; ++r)
                Y[(size_t)(row + r) * 1024 + col] = acc[bm][bn][r] + bb;
        }
    }
}

// ---------------------------------------------------------------------------
// Fused: L2-normalize K,V rows (128) in place AND compute kq[b,h,t] =
// dot(k_normalized, q).  One wave per (b,t,h) row, 2 elems/lane.
// ---------------------------------------------------------------------------
__global__ __launch_bounds__(256) void l2norm_kq(float* __restrict__ Kb,
                                                 float* __restrict__ Vb,
                                                 const float* __restrict__ Qb,
                                                 float* __restrict__ KQ)
{
    const int gtid = blockIdx.x * 256 + threadIdx.x;
    const int row  = gtid >> 6;            // 0 .. B*T*H-1  (b,t,h order)
    const int lane = threadIdx.x & 63;
    const size_t base = (size_t)row * dh + lane * 2;

    float2 k2 = *(float2*)&Kb[base];
    float2 v2 = *(float2*)&Vb[base];
    float2 q2 = *(const float2*)&Qb[base];
    float sk = k2.x * k2.x + k2.y * k2.y;
    float sv = v2.x * v2.x + v2.y * v2.y;
    float sq = k2.x * q2.x + k2.y * q2.y;   // raw k . q
#pragma unroll
    for (int off = 1; off < 64; off <<= 1) {
        sk += __shfl_xor(sk, off);
        sv += __shfl_xor(sv, off);
        sq += __shfl_xor(sq, off);
    }
    const float rk = 1.f / fmaxf(sqrtf(sk), 1e-12f);
    const float rv = 1.f / fmaxf(sqrtf(sv), 1e-12f);
    k2.x *= rk; k2.y *= rk;
    v2.x *= rv; v2.y *= rv;
    *(float2*)&Kb[base] = k2;
    *(float2*)&Vb[base] = v2;
    if (lane == 0) {
        const int b = row / (Tlen * Hh);
        const int t = (row / Hh) % Tlen;
        const int h = row % Hh;
        KQ[(size_t)(b * Hh + h) * Tlen + t] = sq * rk;
    }
}

__global__ __launch_bounds__(256) void sigmoid_k(float* __restrict__ P)
{
    const size_t i = ((size_t)blockIdx.x * 256 + threadIdx.x) * 4;
    float4 v = *(float4*)&P[i];
    v.x = 1.f / (1.f + __expf(-v.x));
    v.y = 1.f / (1.f + __expf(-v.y));
    v.z = 1.f / (1.f + __expf(-v.z));
    v.w = 1.f / (1.f + __expf(-v.w));
    *(float4*)&P[i] = v;
}

// ---------------------------------------------------------------------------
// Delta-rule scan, chain-minimized.
// Wave = 8 rows x 8 lanes; 16 state cols per lane (w[16] in VGPRs).
// Per step:  d1 = w.k, d2 = w.q computed together; only d1's 3-level
// shfl reduce + coef + w-update is on the cross-step chain;
// o = d2 + coef*kq  (kq precomputed) reduced off-path.
// Depth-4 prefetch ring; writes O directly as bf16.
// Grid: 512 blocks (bh = bid&31 keeps same-(b,h) groups on one XCD).
// ---------------------------------------------------------------------------
__global__ __launch_bounds__(64) void scan_kernel(const float* __restrict__ Q,
                                                  const float* __restrict__ Kb,
                                                  const float* __restrict__ Vb,
                                                  const float* __restrict__ LR,
                                                  const float* __restrict__ KQ,
                                                  unsigned short* __restrict__ Obb)
{
    const int bid = blockIdx.x;            // 0..511
    const int bh  = bid & 31;
    const int rg  = bid >> 5;              // 0..15
    const int b   = bh >> 3, h = bh & 7;
    const int lane = threadIdx.x;
    const int rl   = lane >> 3;            // row in group 0..7
    const int c8   = lane & 7;             // col chunk (16 cols)
    const int row  = rg * 8 + rl;

    const size_t base = (size_t)b * Tlen * Dm + (size_t)h * dh;
    const float* kp  = Kb + base + c8 * 16;
    const float* qp  = Q  + base + c8 * 16;
    const float* vp  = Vb + base + row;
    const float* lp  = LR + base + row;
    const float* kqp = KQ + (size_t)(b * Hh + h) * Tlen;
    unsigned short* op = Obb + base + row;

    float w[16];
#pragma unroll
    for (int i = 0; i < 16; ++i) w[i] = 0.f;

    float4 kr[4][4], qr[4][4];
    float  vv[4], lv[4], kqv[4];
#pragma unroll
    for (int u = 0; u < 4; ++u) {
        const size_t off = (size_t)u * Dm;
#pragma unroll
        for (int c = 0; c < 4; ++c) {
            kr[u][c] = *(const float4*)(kp + off + c * 4);
            qr[u][c] = *(const float4*)(qp + off + c * 4);
        }
        vv[u] = vp[off];
        lv[u] = lp[off];
        kqv[u] = kqp[u];
    }

    for (int t = 0; t < Tlen; t += 4) {
#pragma unroll
        for (int u = 0; u < 4; ++u) {
            const int tc = t + u;
            float4 k0 = kr[u][0], k1 = kr[u][1], k2 = kr[u][2], k3 = kr[u][3];
            float4 q0 = qr[u][0], q1 = qr[u][1], q2 = qr[u][2], q3 = qr[u][3];
            const float vr = vv[u], lrr = lv[u], kq = kqv[u];

            // prefetch tc+4 into freed slot u (regs copied above)
            int tn = tc + 4; if (tn >= Tlen) tn = Tlen - 1;
            const size_t offn = (size_t)tn * Dm;
#pragma unroll
            for (int c = 0; c < 4; ++c) {
                kr[u][c] = *(const float4*)(kp + offn + c * 4);
                qr[u][c] = *(const float4*)(qp + offn + c * 4);
            }
            vv[u] = vp[offn];
            lv[u] = lp[offn];
            kqv[u] = kqp[tn];

            // partial dots (4 independent accumulator chains each)
            float d1 = ((fmaf(w[1], k0.y, w[0] * k0.x) + fmaf(w[3], k0.w, w[2] * k0.z)) +
                        (fmaf(w[5], k1.y, w[4] * k1.x) + fmaf(w[7], k1.w, w[6] * k1.z))) +
                       ((fmaf(w[9], k2.y, w[8] * k2.x) + fmaf(w[11], k2.w, w[10] * k2.z)) +
                        (fmaf(w[13], k3.y, w[12] * k3.x) + fmaf(w[15], k3.w, w[14] * k3.z)));
            float d2 = ((fmaf(w[1], q0.y, w[0] * q0.x) + fmaf(w[3], q0.w, w[2] * q0.z)) +
                        (fmaf(w[5], q1.y, w[4] * q1.x) + fmaf(w[7], q1.w, w[6] * q1.z))) +
                       ((fmaf(w[9], q2.y, w[8] * q2.x) + fmaf(w[11], q2.w, w[10] * q2.z)) +
                        (fmaf(w[13], q3.y, w[12] * q3.x) + fmaf(w[15], q3.w, w[14] * q3.z)));

            // critical-path reduce: d1 only (3 levels within 8 lanes)
            d1 += __shfl_xor(d1, 1, 8);
            d1 += __shfl_xor(d1, 2, 8);
            d1 += __shfl_xor(d1, 4, 8);
            const float coef = lrr * (vr - d1);

            // w update (feeds next step's dot)
            w[0]  = fmaf(coef, k0.x, w[0]);  w[1]  = fmaf(coef, k0.y, w[1]);
            w[2]  = fmaf(coef, k0.z, w[2]);  w[3]  = fmaf(coef, k0.w, w[3]);
            w[4]  = fmaf(coef, k1.x, w[4]);  w[5]  = fmaf(coef, k1.y, w[5]);
            w[6]  = fmaf(coef, k1.z, w[6]);  w[7]  = fmaf(coef, k1.w, w[7]);
            w[8]  = fmaf(coef, k2.x, w[8]);  w[9]  = fmaf(coef, k2.y, w[9]);
            w[10] = fmaf(coef, k2.z, w[10]); w[11] = fmaf(coef, k2.w, w[11]);
            w[12] = fmaf(coef, k3.x, w[12]); w[13] = fmaf(coef, k3.y, w[13]);
            w[14] = fmaf(coef, k3.z, w[14]); w[15] = fmaf(coef, k3.w, w[15]);

            // off-path: reduce d2 and emit o = w_old.q + coef*(k.q)
            d2 += __shfl_xor(d2, 1, 8);
            d2 += __shfl_xor(d2, 2, 8);
            d2 += __shfl_xor(d2, 4, 8);
            const float o = fmaf(coef, kq, d2);
            if (c8 == 0) op[(size_t)tc * Dm] = f2b_rne(o);
        }
    }
}

// ---------------------------------------------------------------------------
extern "C" void kernel_launch(void* const* d_in, const int* in_sizes, int n_in,
                              void* d_out, int out_size, void* d_ws, size_t ws_size,
                              hipStream_t stream)
{
    const float* x    = (const float*)d_in[0];
    const float* Wq   = (const float*)d_in[1];
    const float* Wk   = (const float*)d_in[2];
    const float* Wv   = (const float*)d_in[3];
    const float* Wo   = (const float*)d_in[4];
    const float* Wlr  = (const float*)d_in[5];
    const float* b_lr = (const float*)d_in[6];

    float* ws = (float*)d_ws;
    const size_t S  = (size_t)Mrows * Dm;    // 8388608
    const size_t SW = (size_t)Dm * Dm;       // 1048576
    float* Qb  = ws;
    float* Kb  = ws + S;
    float* Vb  = ws + 2 * S;
    float* LRb = ws + 3 * S;
    unsigned short* xb  = (unsigned short*)(ws + 4 * S);   // S bf16
    unsigned short* Obb = xb;                              // alias: xb dead before scan
    unsigned short* Wqb  = (unsigned short*)(ws + 4 * S + S / 2);
    unsigned short* Wkb  = Wqb + SW;
    unsigned short* Wvb  = Wkb + SW;
    unsigned short* Wlrb = Wvb + SW;
    unsigned short* Wob  = Wlrb + SW;
    float* KQ = (float*)(Wob + SW);          // B*H*T floats

    cvt_f32_bf16<<<S / 1024, 256, 0, stream>>>(x, xb);
    cvt_f32_bf16<<<SW / 1024, 256, 0, stream>>>(Wq, Wqb);
    cvt_f32_bf16<<<SW / 1024, 256, 0, stream>>>(Wk, Wkb);
    cvt_f32_bf16<<<SW / 1024, 256, 0, stream>>>(Wv, Wvb);
    cvt_f32_bf16<<<SW / 1024, 256, 0, stream>>>(Wlr, Wlrb);
    cvt_f32_bf16<<<SW / 1024, 256, 0, stream>>>(Wo, Wob);

    dim3 gg(Dm / 128, Mrows / 128);   // (8, 64)
    gemm_bf16<<<gg, 256, 0, stream>>>(xb, Wqb, nullptr, Qb);
    gemm_bf16<<<gg, 256, 0, stream>>>(xb, Wkb, nullptr, Kb);
    gemm_bf16<<<gg, 256, 0, stream>>>(xb, Wvb, nullptr, Vb);
    gemm_bf16<<<gg, 256, 0, stream>>>(xb, Wlrb, b_lr, LRb);

    l2norm_kq<<<(Bsz * Tlen * Hh) / 4, 256, 0, stream>>>(Kb, Vb, Qb, KQ);
    sigmoid_k<<<S / 1024, 256, 0, stream>>>(LRb);

    scan_kernel<<<Bsz * Hh * 16, 64, 0, stream>>>(Qb, Kb, Vb, LRb, KQ, Obb);

    gemm_bf16<<<gg, 256, 0, stream>>>(Obb, Wob, nullptr, (float*)d_out);
}

// Round 4
// 988.176 us; speedup vs baseline: 2.6789x; 1.1232x over previous
//
#include <hip/hip_runtime.h>
#include <math.h>

#define Bsz  4
#define Tlen 2048
#define Dm   1024
#define Hh   8
#define dh   128
#define Mrows (Bsz * Tlen)   // 8192

typedef __attribute__((ext_vector_type(8))) short  s16x8;
typedef __attribute__((ext_vector_type(4))) float  f32x4;

// DPP cross-lane add at VALU latency (no LDS pipe).
// ctrl: 0xB1 = quad_perm[1,0,3,2] (xor1), 0x4E = quad_perm[2,3,0,1] (xor2),
//       0x141 = row_half_mirror (i <-> 7-i within 8; acts as xor4 once quads
//       are uniform), 0x140 = row_mirror.
#define DPP_ADD(x, ctrl) \
    ((x) + __int_as_float(__builtin_amdgcn_update_dpp( \
        0, __float_as_int(x), (ctrl), 0xf, 0xf, true)))

// ---------------------------------------------------------------------------
// fp32 -> bf16 (RNE)
// ---------------------------------------------------------------------------
__device__ inline unsigned short f2b_rne(float f) {
    unsigned int u = __float_as_uint(f);
    u += 0x7FFFu + ((u >> 16) & 1u);
    return (unsigned short)(u >> 16);
}

__global__ __launch_bounds__(256) void cvt_f32_bf16(const float* __restrict__ in,
                                                    unsigned short* __restrict__ out)
{
    const size_t i = ((size_t)blockIdx.x * 256 + threadIdx.x) * 4;
    float4 v = *(const float4*)&in[i];
    ushort4 o;
    o.x = f2b_rne(v.x); o.y = f2b_rne(v.y);
    o.z = f2b_rne(v.z); o.w = f2b_rne(v.w);
    *(ushort4*)&out[i] = o;
}

// ---------------------------------------------------------------------------
// bf16 MFMA GEMM (m97 recipe): Y[m][n] = sum_k A[m][k]*W[n][k] (+bias[n])
// ---------------------------------------------------------------------------
__global__ __launch_bounds__(256) void gemm_bf16(const unsigned short* __restrict__ A,
                                                 const unsigned short* __restrict__ Wt,
                                                 const float* __restrict__ bias,
                                                 float* __restrict__ Y)
{
    __shared__ __align__(16) unsigned short As[128 * 32];
    __shared__ __align__(16) unsigned short Bs[128 * 32];

    const int tid   = threadIdx.x;
    const int w     = tid >> 6;
    const int lane  = tid & 63;
    const int r4    = lane >> 2;
    const int p4    = lane & 3;
    const int row16 = lane & 15;
    const int quad  = lane >> 4;

    const int m0 = blockIdx.y * 128;
    const int n0 = blockIdx.x * 128;
    const int wm = (w >> 1) * 64;
    const int wn = (w & 1) * 64;

    f32x4 acc[4][4];
#pragma unroll
    for (int i = 0; i < 4; ++i)
#pragma unroll
        for (int j = 0; j < 4; ++j)
            acc[i][j] = (f32x4){0.f, 0.f, 0.f, 0.f};

    for (int k0 = 0; k0 < 1024; k0 += 32) {
        __syncthreads();
#pragma unroll
        for (int c = 0; c < 2; ++c) {
            const int ml  = w * 32 + c * 16 + r4;
            const int swz = (ml >> 1) & 3;
            const unsigned short* ga = A  + (size_t)(m0 + ml) * 1024 + k0 + ((p4 ^ swz) << 3);
            const unsigned short* gb = Wt + (size_t)(n0 + ml) * 1024 + k0 + ((p4 ^ swz) << 3);
            __builtin_amdgcn_global_load_lds(
                (const __attribute__((address_space(1))) void*)ga,
                (__attribute__((address_space(3))) void*)&As[(w * 32 + c * 16) * 32], 16, 0, 0);
            __builtin_amdgcn_global_load_lds(
                (const __attribute__((address_space(1))) void*)gb,
                (__attribute__((address_space(3))) void*)&Bs[(w * 32 + c * 16) * 32], 16, 0, 0);
        }
        __syncthreads();

        s16x8 af[4], bf[4];
#pragma unroll
        for (int bm = 0; bm < 4; ++bm) {
            const int ml  = wm + bm * 16 + row16;
            const int pos = quad ^ ((ml >> 1) & 3);
            af[bm] = *(const s16x8*)&As[ml * 32 + pos * 8];
        }
#pragma unroll
        for (int bn = 0; bn < 4; ++bn) {
            const int nl  = wn + bn * 16 + row16;
            const int pos = quad ^ ((nl >> 1) & 3);
            bf[bn] = *(const s16x8*)&Bs[nl * 32 + pos * 8];
        }
#pragma unroll
        for (int bm = 0; bm < 4; ++bm)
#pragma unroll
            for (int bn = 0; bn < 4; ++bn)
                acc[bm][bn] = __builtin_amdgcn_mfma_f32_16x16x32_bf16(af[bm], bf[bn], acc[bm][bn], 0, 0, 0);
    }

#pragma unroll
    for (int bm = 0; bm < 4; ++bm) {
        const int row = m0 + wm + bm * 16 + quad * 4;
#pragma unroll
        for (int bn = 0; bn < 4; ++bn) {
            const int col = n0 + wn + bn * 16 + row16;
            const float bb = bias ? bias[col] : 0.f;
#pragma unroll
            for (int r = 0; r < 4; ++r)
                Y[(size_t)(row + r) * 1024 + col] = acc[bm][bn][r] + bb;
        }
    }
}

// ---------------------------------------------------------------------------
// Fused: L2-normalize K,V rows (128) in place AND kq[b,h,t] = k_norm . q
// ---------------------------------------------------------------------------
__global__ __launch_bounds__(256) void l2norm_kq(float* __restrict__ Kb,
                                                 float* __restrict__ Vb,
                                                 const float* __restrict__ Qb,
                                                 float* __restrict__ KQ)
{
    const int gtid = blockIdx.x * 256 + threadIdx.x;
    const int row  = gtid >> 6;            // 0 .. B*T*H-1  (b,t,h order)
    const int lane = threadIdx.x & 63;
    const size_t base = (size_t)row * dh + lane * 2;

    float2 k2 = *(float2*)&Kb[base];
    float2 v2 = *(float2*)&Vb[base];
    float2 q2 = *(const float2*)&Qb[base];
    float sk = k2.x * k2.x + k2.y * k2.y;
    float sv = v2.x * v2.x + v2.y * v2.y;
    float sq = k2.x * q2.x + k2.y * q2.y;
#pragma unroll
    for (int off = 1; off < 64; off <<= 1) {
        sk += __shfl_xor(sk, off);
        sv += __shfl_xor(sv, off);
        sq += __shfl_xor(sq, off);
    }
    const float rk = 1.f / fmaxf(sqrtf(sk), 1e-12f);
    const float rv = 1.f / fmaxf(sqrtf(sv), 1e-12f);
    k2.x *= rk; k2.y *= rk;
    v2.x *= rv; v2.y *= rv;
    *(float2*)&Kb[base] = k2;
    *(float2*)&Vb[base] = v2;
    if (lane == 0) {
        const int b = row / (Tlen * Hh);
        const int t = (row / Hh) % Tlen;
        const int h = row % Hh;
        KQ[(size_t)(b * Hh + h) * Tlen + t] = sq * rk;
    }
}

__global__ __launch_bounds__(256) void sigmoid_k(float* __restrict__ P)
{
    const size_t i = ((size_t)blockIdx.x * 256 + threadIdx.x) * 4;
    float4 v = *(float4*)&P[i];
    v.x = 1.f / (1.f + __expf(-v.x));
    v.y = 1.f / (1.f + __expf(-v.y));
    v.z = 1.f / (1.f + __expf(-v.z));
    v.w = 1.f / (1.f + __expf(-v.w));
    *(float4*)&P[i] = v;
}

// ---------------------------------------------------------------------------
// Delta-rule scan.  Wave = 8 rows x 8 lanes, 16 state cols/lane.
// Cross-lane reduction via DPP (VALU latency) instead of ds_swizzle:
//   xor1 = quad_perm[1,0,3,2], xor2 = quad_perm[2,3,0,1],
//   xor4 = row_half_mirror (valid once quads are uniform).
// Off-chain output: o = w_old.q + coef*(k.q), kq precomputed.
// ---------------------------------------------------------------------------
__global__ __launch_bounds__(64) void scan_kernel(const float* __restrict__ Q,
                                                  const float* __restrict__ Kb,
                                                  const float* __restrict__ Vb,
                                                  const float* __restrict__ LR,
                                                  const float* __restrict__ KQ,
                                                  unsigned short* __restrict__ Obb)
{
    const int bid = blockIdx.x;            // 0..511
    const int bh  = bid & 31;
    const int rg  = bid >> 5;              // 0..15
    const int b   = bh >> 3, h = bh & 7;
    const int lane = threadIdx.x;
    const int rl   = lane >> 3;            // row in group 0..7
    const int c8   = lane & 7;             // col chunk (16 cols)
    const int row  = rg * 8 + rl;

    const size_t base = (size_t)b * Tlen * Dm + (size_t)h * dh;
    const float* kp  = Kb + base + c8 * 16;
    const float* qp  = Q  + base + c8 * 16;
    const float* vp  = Vb + base + row;
    const float* lp  = LR + base + row;
    const float* kqp = KQ + (size_t)(b * Hh + h) * Tlen;
    unsigned short* op = Obb + base + row;

    float w[16];
#pragma unroll
    for (int i = 0; i < 16; ++i) w[i] = 0.f;

    float4 kr[4][4], qr[4][4];
    float  vv[4], lv[4], kqv[4];
#pragma unroll
    for (int u = 0; u < 4; ++u) {
        const size_t off = (size_t)u * Dm;
#pragma unroll
        for (int c = 0; c < 4; ++c) {
            kr[u][c] = *(const float4*)(kp + off + c * 4);
            qr[u][c] = *(const float4*)(qp + off + c * 4);
        }
        vv[u] = vp[off];
        lv[u] = lp[off];
        kqv[u] = kqp[u];
    }

    for (int t = 0; t < Tlen; t += 4) {
#pragma unroll
        for (int u = 0; u < 4; ++u) {
            const int tc = t + u;
            float4 k0 = kr[u][0], k1 = kr[u][1], k2 = kr[u][2], k3 = kr[u][3];
            float4 q0 = qr[u][0], q1 = qr[u][1], q2 = qr[u][2], q3 = qr[u][3];
            const float vr = vv[u], lrr = lv[u], kq = kqv[u];

            // prefetch tc+4 into freed slot u
            int tn = tc + 4; if (tn >= Tlen) tn = Tlen - 1;
            const size_t offn = (size_t)tn * Dm;
#pragma unroll
            for (int c = 0; c < 4; ++c) {
                kr[u][c] = *(const float4*)(kp + offn + c * 4);
                qr[u][c] = *(const float4*)(qp + offn + c * 4);
            }
            vv[u] = vp[offn];
            lv[u] = lp[offn];
            kqv[u] = kqp[tn];

            // partial dots
            float d1 = ((fmaf(w[1], k0.y, w[0] * k0.x) + fmaf(w[3], k0.w, w[2] * k0.z)) +
                        (fmaf(w[5], k1.y, w[4] * k1.x) + fmaf(w[7], k1.w, w[6] * k1.z))) +
                       ((fmaf(w[9], k2.y, w[8] * k2.x) + fmaf(w[11], k2.w, w[10] * k2.z)) +
                        (fmaf(w[13], k3.y, w[12] * k3.x) + fmaf(w[15], k3.w, w[14] * k3.z)));
            float d2 = ((fmaf(w[1], q0.y, w[0] * q0.x) + fmaf(w[3], q0.w, w[2] * q0.z)) +
                        (fmaf(w[5], q1.y, w[4] * q1.x) + fmaf(w[7], q1.w, w[6] * q1.z))) +
                       ((fmaf(w[9], q2.y, w[8] * q2.x) + fmaf(w[11], q2.w, w[10] * q2.z)) +
                        (fmaf(w[13], q3.y, w[12] * q3.x) + fmaf(w[15], q3.w, w[14] * q3.z)));

            // critical-path reduce: d1 via DPP (VALU latency)
            d1 = DPP_ADD(d1, 0xB1);    // xor1
            d1 = DPP_ADD(d1, 0x4E);    // xor2
            d1 = DPP_ADD(d1, 0x141);   // half-mirror == xor4 here
            const float coef = lrr * (vr - d1);

            // w update (feeds next step's dot)
            w[0]  = fmaf(coef, k0.x, w[0]);  w[1]  = fmaf(coef, k0.y, w[1]);
            w[2]  = fmaf(coef, k0.z, w[2]);  w[3]  = fmaf(coef, k0.w, w[3]);
            w[4]  = fmaf(coef, k1.x, w[4]);  w[5]  = fmaf(coef, k1.y, w[5]);
            w[6]  = fmaf(coef, k1.z, w[6]);  w[7]  = fmaf(coef, k1.w, w[7]);
            w[8]  = fmaf(coef, k2.x, w[8]);  w[9]  = fmaf(coef, k2.y, w[9]);
            w[10] = fmaf(coef, k2.z, w[10]); w[11] = fmaf(coef, k2.w, w[11]);
            w[12] = fmaf(coef, k3.x, w[12]); w[13] = fmaf(coef, k3.y, w[13]);
            w[14] = fmaf(coef, k3.z, w[14]); w[15] = fmaf(coef, k3.w, w[15]);

            // off-path: d2 reduce via DPP, emit o = w_old.q + coef*(k.q)
            d2 = DPP_ADD(d2, 0xB1);
            d2 = DPP_ADD(d2, 0x4E);
            d2 = DPP_ADD(d2, 0x141);
            const float o = fmaf(coef, kq, d2);
            if (c8 == 0) op[(size_t)tc * Dm] = f2b_rne(o);
        }
    }
}

// ---------------------------------------------------------------------------
extern "C" void kernel_launch(void* const* d_in, const int* in_sizes, int n_in,
                              void* d_out, int out_size, void* d_ws, size_t ws_size,
                              hipStream_t stream)
{
    const float* x    = (const float*)d_in[0];
    const float* Wq   = (const float*)d_in[1];
    const float* Wk   = (const float*)d_in[2];
    const float* Wv   = (const float*)d_in[3];
    const float* Wo   = (const float*)d_in[4];
    const float* Wlr  = (const float*)d_in[5];
    const float* b_lr = (const float*)d_in[6];

    float* ws = (float*)d_ws;
    const size_t S  = (size_t)Mrows * Dm;    // 8388608
    const size_t SW = (size_t)Dm * Dm;       // 1048576
    float* Qb  = ws;
    float* Kb  = ws + S;
    float* Vb  = ws + 2 * S;
    float* LRb = ws + 3 * S;
    unsigned short* xb  = (unsigned short*)(ws + 4 * S);   // S bf16
    unsigned short* Obb = xb;                              // alias: xb dead before scan
    unsigned short* Wqb  = (unsigned short*)(ws + 4 * S + S / 2);
    unsigned short* Wkb  = Wqb + SW;
    unsigned short* Wvb  = Wkb + SW;
    unsigned short* Wlrb = Wvb + SW;
    unsigned short* Wob  = Wlrb + SW;
    float* KQ = (float*)(Wob + SW);          // B*H*T floats

    cvt_f32_bf16<<<S / 1024, 256, 0, stream>>>(x, xb);
    cvt_f32_bf16<<<SW / 1024, 256, 0, stream>>>(Wq, Wqb);
    cvt_f32_bf16<<<SW / 1024, 256, 0, stream>>>(Wk, Wkb);
    cvt_f32_bf16<<<SW / 1024, 256, 0, stream>>>(Wv, Wvb);
    cvt_f32_bf16<<<SW / 1024, 256, 0, stream>>>(Wlr, Wlrb);
    cvt_f32_bf16<<<SW / 1024, 256, 0, stream>>>(Wo, Wob);

    dim3 gg(Dm / 128, Mrows / 128);   // (8, 64)
    gemm_bf16<<<gg, 256, 0, stream>>>(xb, Wqb, nullptr, Qb);
    gemm_bf16<<<gg, 256, 0, stream>>>(xb, Wkb, nullptr, Kb);
    gemm_bf16<<<gg, 256, 0, stream>>>(xb, Wvb, nullptr, Vb);
    gemm_bf16<<<gg, 256, 0, stream>>>(xb, Wlrb, b_lr, LRb);

    l2norm_kq<<<(Bsz * Tlen * Hh) / 4, 256, 0, stream>>>(Kb, Vb, Qb, KQ);
    sigmoid_k<<<S / 1024, 256, 0, stream>>>(LRb);

    scan_kernel<<<Bsz * Hh * 16, 64, 0, stream>>>(Qb, Kb, Vb, LRb, KQ, Obb);

    gemm_bf16<<<gg, 256, 0, stream>>>(Obb, Wob, nullptr, (float*)d_out);
}

// Round 5
// 681.637 us; speedup vs baseline: 3.8836x; 1.4497x over previous
//
#include <hip/hip_runtime.h>
#include <math.h>

#define Bsz  4
#define Tlen 2048
#define Dm   1024
#define Hh   8
#define dh   128
#define Mrows (Bsz * Tlen)   // 8192

typedef __attribute__((ext_vector_type(8))) short  s16x8;
typedef __attribute__((ext_vector_type(4))) float  f32x4;

// DPP cross-lane add at VALU latency.
// 0xB1 quad_perm[1,0,3,2]=xor1; 0x4E quad_perm[2,3,0,1]=xor2;
// 0x141 row_half_mirror (==xor4 once quads uniform); 0x140 row_mirror (==xor8).
#define DPP_ADD(x, ctrl) \
    ((x) + __int_as_float(__builtin_amdgcn_update_dpp( \
        0, __float_as_int(x), (ctrl), 0xf, 0xf, true)))

// ---------------------------------------------------------------------------
__device__ inline unsigned short f2b_rne(float f) {
    unsigned int u = __float_as_uint(f);
    u += 0x7FFFu + ((u >> 16) & 1u);
    return (unsigned short)(u >> 16);
}

__global__ __launch_bounds__(256) void cvt_f32_bf16(const float* __restrict__ in,
                                                    unsigned short* __restrict__ out)
{
    const size_t i = ((size_t)blockIdx.x * 256 + threadIdx.x) * 4;
    float4 v = *(const float4*)&in[i];
    ushort4 o;
    o.x = f2b_rne(v.x); o.y = f2b_rne(v.y);
    o.z = f2b_rne(v.z); o.w = f2b_rne(v.w);
    *(ushort4*)&out[i] = o;
}

// ---------------------------------------------------------------------------
// bf16 MFMA GEMM: Y[m][n] = sum_k A[m][k]*W[n][k] (+bias); mode1: sigmoid(.)
// ---------------------------------------------------------------------------
__global__ __launch_bounds__(256) void gemm_bf16(const unsigned short* __restrict__ A,
                                                 const unsigned short* __restrict__ Wt,
                                                 const float* __restrict__ bias,
                                                 float* __restrict__ Y,
                                                 int mode)
{
    __shared__ __align__(16) unsigned short As[128 * 32];
    __shared__ __align__(16) unsigned short Bs[128 * 32];

    const int tid   = threadIdx.x;
    const int w     = tid >> 6;
    const int lane  = tid & 63;
    const int r4    = lane >> 2;
    const int p4    = lane & 3;
    const int row16 = lane & 15;
    const int quad  = lane >> 4;

    const int m0 = blockIdx.y * 128;
    const int n0 = blockIdx.x * 128;
    const int wm = (w >> 1) * 64;
    const int wn = (w & 1) * 64;

    f32x4 acc[4][4];
#pragma unroll
    for (int i = 0; i < 4; ++i)
#pragma unroll
        for (int j = 0; j < 4; ++j)
            acc[i][j] = (f32x4){0.f, 0.f, 0.f, 0.f};

    for (int k0 = 0; k0 < 1024; k0 += 32) {
        __syncthreads();
#pragma unroll
        for (int c = 0; c < 2; ++c) {
            const int ml  = w * 32 + c * 16 + r4;
            const int swz = (ml >> 1) & 3;
            const unsigned short* ga = A  + (size_t)(m0 + ml) * 1024 + k0 + ((p4 ^ swz) << 3);
            const unsigned short* gb = Wt + (size_t)(n0 + ml) * 1024 + k0 + ((p4 ^ swz) << 3);
            __builtin_amdgcn_global_load_lds(
                (const __attribute__((address_space(1))) void*)ga,
                (__attribute__((address_space(3))) void*)&As[(w * 32 + c * 16) * 32], 16, 0, 0);
            __builtin_amdgcn_global_load_lds(
                (const __attribute__((address_space(1))) void*)gb,
                (__attribute__((address_space(3))) void*)&Bs[(w * 32 + c * 16) * 32], 16, 0, 0);
        }
        __syncthreads();

        s16x8 af[4], bf[4];
#pragma unroll
        for (int bm = 0; bm < 4; ++bm) {
            const int ml  = wm + bm * 16 + row16;
            const int pos = quad ^ ((ml >> 1) & 3);
            af[bm] = *(const s16x8*)&As[ml * 32 + pos * 8];
        }
#pragma unroll
        for (int bn = 0; bn < 4; ++bn) {
            const int nl  = wn + bn * 16 + row16;
            const int pos = quad ^ ((nl >> 1) & 3);
            bf[bn] = *(const s16x8*)&Bs[nl * 32 + pos * 8];
        }
#pragma unroll
        for (int bm = 0; bm < 4; ++bm)
#pragma unroll
            for (int bn = 0; bn < 4; ++bn)
                acc[bm][bn] = __builtin_amdgcn_mfma_f32_16x16x32_bf16(af[bm], bf[bn], acc[bm][bn], 0, 0, 0);
    }

#pragma unroll
    for (int bm = 0; bm < 4; ++bm) {
        const int row = m0 + wm + bm * 16 + quad * 4;
#pragma unroll
        for (int bn = 0; bn < 4; ++bn) {
            const int col = n0 + wn + bn * 16 + row16;
            const float bb = bias ? bias[col] : 0.f;
#pragma unroll
            for (int r = 0; r < 4; ++r) {
                float val = acc[bm][bn][r] + bb;
                if (mode == 1) val = 1.f / (1.f + __expf(-val));
                Y[(size_t)(row + r) * 1024 + col] = val;
            }
        }
    }
}

// ---------------------------------------------------------------------------
// Fused: L2-normalize K,V rows in place AND kq[b,h,t] = k_norm . q
// ---------------------------------------------------------------------------
__global__ __launch_bounds__(256) void l2norm_kq(float* __restrict__ Kb,
                                                 float* __restrict__ Vb,
                                                 const float* __restrict__ Qb,
                                                 float* __restrict__ KQ)
{
    const int gtid = blockIdx.x * 256 + threadIdx.x;
    const int row  = gtid >> 6;            // 0 .. B*T*H-1  (b,t,h order)
    const int lane = threadIdx.x & 63;
    const size_t base = (size_t)row * dh + lane * 2;

    float2 k2 = *(float2*)&Kb[base];
    float2 v2 = *(float2*)&Vb[base];
    float2 q2 = *(const float2*)&Qb[base];
    float sk = k2.x * k2.x + k2.y * k2.y;
    float sv = v2.x * v2.x + v2.y * v2.y;
    float sq = k2.x * q2.x + k2.y * q2.y;
#pragma unroll
    for (int off = 1; off < 64; off <<= 1) {
        sk += __shfl_xor(sk, off);
        sv += __shfl_xor(sv, off);
        sq += __shfl_xor(sq, off);
    }
    const float rk = 1.f / fmaxf(sqrtf(sk), 1e-12f);
    const float rv = 1.f / fmaxf(sqrtf(sv), 1e-12f);
    k2.x *= rk; k2.y *= rk;
    v2.x *= rv; v2.y *= rv;
    *(float2*)&Kb[base] = k2;
    *(float2*)&Vb[base] = v2;
    if (lane == 0) {
        const int b = row / (Tlen * Hh);
        const int t = (row / Hh) % Tlen;
        const int h = row % Hh;
        KQ[(size_t)(b * Hh + h) * Tlen + t] = sq * rk;
    }
}

// ---------------------------------------------------------------------------
// Delta-rule scan v3.
// Wave = 4 rows x 16 lanes, 8 state cols/lane (w[8]).  1024 waves (1/SIMD).
// DPP butterfly (xor1,xor2,xor4,xor8) leaves full sum in ALL 16 lanes.
// Stores batched 8:1 — o kept in regs, per-lane cndmask select, single
// masked scatter-store (lanes c16<8) per 8 steps -> 8x less vmcnt-FIFO
// pollution from store retires.
// Prefetch ring depth 8.
// ---------------------------------------------------------------------------
__global__ __launch_bounds__(64) void scan_kernel(const float* __restrict__ Q,
                                                  const float* __restrict__ Kb,
                                                  const float* __restrict__ Vb,
                                                  const float* __restrict__ LR,
                                                  const float* __restrict__ KQ,
                                                  unsigned short* __restrict__ Obb)
{
    const int bid = blockIdx.x;            // 0..1023
    const int bh  = bid & 31;              // same-bh blocks share an XCD
    const int rg  = bid >> 5;              // 0..31
    const int b   = bh >> 3, h = bh & 7;
    const int lane = threadIdx.x;
    const int rl   = lane >> 4;            // row in group 0..3
    const int c16  = lane & 15;            // col chunk (8 cols)
    const int row  = rg * 4 + rl;

    const size_t base = (size_t)b * Tlen * Dm + (size_t)h * dh;
    const float* kp  = Kb + base + c16 * 8;
    const float* qp  = Q  + base + c16 * 8;
    const float* vp  = Vb + base + row;
    const float* lp  = LR + base + row;
    const float* kqp = KQ + (size_t)(b * Hh + h) * Tlen;
    unsigned short* op = Obb + base + row;

    float w[8];
#pragma unroll
    for (int i = 0; i < 8; ++i) w[i] = 0.f;

    // prefetch ring, depth 8
    float4 kr[8][2], qr[8][2];
    float  vv[8], lv[8], kqv[8];
#pragma unroll
    for (int u = 0; u < 8; ++u) {
        const size_t off = (size_t)u * Dm;
        kr[u][0] = *(const float4*)(kp + off);
        kr[u][1] = *(const float4*)(kp + off + 4);
        qr[u][0] = *(const float4*)(qp + off);
        qr[u][1] = *(const float4*)(qp + off + 4);
        vv[u] = vp[off];
        lv[u] = lp[off];
        kqv[u] = kqp[u];
    }

    float o8[8];

    for (int t = 0; t < Tlen; t += 8) {
#pragma unroll
        for (int u = 0; u < 8; ++u) {
            const int tc = t + u;
            const float4 ka = kr[u][0], kb = kr[u][1];
            const float4 qa = qr[u][0], qb = qr[u][1];
            const float vr = vv[u], lrr = lv[u], kq = kqv[u];

            // prefetch tc+8 into freed slot u
            int tn = tc + 8; if (tn >= Tlen) tn = Tlen - 1;
            const size_t offn = (size_t)tn * Dm;
            kr[u][0] = *(const float4*)(kp + offn);
            kr[u][1] = *(const float4*)(kp + offn + 4);
            qr[u][0] = *(const float4*)(qp + offn);
            qr[u][1] = *(const float4*)(qp + offn + 4);
            vv[u] = vp[offn];
            lv[u] = lp[offn];
            kqv[u] = kqp[tn];

            // partial dots over this lane's 8 cols
            float d1 = (fmaf(w[1], ka.y, w[0] * ka.x) + fmaf(w[3], ka.w, w[2] * ka.z)) +
                       (fmaf(w[5], kb.y, w[4] * kb.x) + fmaf(w[7], kb.w, w[6] * kb.z));
            float d2 = (fmaf(w[1], qa.y, w[0] * qa.x) + fmaf(w[3], qa.w, w[2] * qa.z)) +
                       (fmaf(w[5], qb.y, w[4] * qb.x) + fmaf(w[7], qb.w, w[6] * qb.z));

            // critical path: d1 butterfly (all-lane result), coef, w update
            d1 = DPP_ADD(d1, 0xB1);
            d1 = DPP_ADD(d1, 0x4E);
            d1 = DPP_ADD(d1, 0x141);
            d1 = DPP_ADD(d1, 0x140);
            const float coef = lrr * (vr - d1);

            w[0] = fmaf(coef, ka.x, w[0]); w[1] = fmaf(coef, ka.y, w[1]);
            w[2] = fmaf(coef, ka.z, w[2]); w[3] = fmaf(coef, ka.w, w[3]);
            w[4] = fmaf(coef, kb.x, w[4]); w[5] = fmaf(coef, kb.y, w[5]);
            w[6] = fmaf(coef, kb.z, w[6]); w[7] = fmaf(coef, kb.w, w[7]);

            // off-path: d2 butterfly, o = w_old.q + coef*(k.q)
            d2 = DPP_ADD(d2, 0xB1);
            d2 = DPP_ADD(d2, 0x4E);
            d2 = DPP_ADD(d2, 0x141);
            d2 = DPP_ADD(d2, 0x140);
            o8[u] = fmaf(coef, kq, d2);
        }

        // batched store: lane c16 (<8) takes o8[c16], one scatter-store
        float sel = o8[0];
#pragma unroll
        for (int j = 1; j < 8; ++j)
            sel = (c16 == j) ? o8[j] : sel;
        if (c16 < 8)
            op[(size_t)(t + c16) * Dm] = f2b_rne(sel);
    }
}

// ---------------------------------------------------------------------------
extern "C" void kernel_launch(void* const* d_in, const int* in_sizes, int n_in,
                              void* d_out, int out_size, void* d_ws, size_t ws_size,
                              hipStream_t stream)
{
    const float* x    = (const float*)d_in[0];
    const float* Wq   = (const float*)d_in[1];
    const float* Wk   = (const float*)d_in[2];
    const float* Wv   = (const float*)d_in[3];
    const float* Wo   = (const float*)d_in[4];
    const float* Wlr  = (const float*)d_in[5];
    const float* b_lr = (const float*)d_in[6];

    float* ws = (float*)d_ws;
    const size_t S  = (size_t)Mrows * Dm;    // 8388608
    const size_t SW = (size_t)Dm * Dm;       // 1048576
    float* Qb  = ws;
    float* Kb  = ws + S;
    float* Vb  = ws + 2 * S;
    float* LRb = ws + 3 * S;
    unsigned short* xb  = (unsigned short*)(ws + 4 * S);   // S bf16
    unsigned short* Obb = xb;                              // alias: xb dead before scan
    unsigned short* Wqb  = (unsigned short*)(ws + 4 * S + S / 2);
    unsigned short* Wkb  = Wqb + SW;
    unsigned short* Wvb  = Wkb + SW;
    unsigned short* Wlrb = Wvb + SW;
    unsigned short* Wob  = Wlrb + SW;
    float* KQ = (float*)(Wob + SW);          // B*H*T floats

    cvt_f32_bf16<<<S / 1024, 256, 0, stream>>>(x, xb);
    cvt_f32_bf16<<<SW / 1024, 256, 0, stream>>>(Wq, Wqb);
    cvt_f32_bf16<<<SW / 1024, 256, 0, stream>>>(Wk, Wkb);
    cvt_f32_bf16<<<SW / 1024, 256, 0, stream>>>(Wv, Wvb);
    cvt_f32_bf16<<<SW / 1024, 256, 0, stream>>>(Wlr, Wlrb);
    cvt_f32_bf16<<<SW / 1024, 256, 0, stream>>>(Wo, Wob);

    dim3 gg(Dm / 128, Mrows / 128);   // (8, 64)
    gemm_bf16<<<gg, 256, 0, stream>>>(xb, Wqb, nullptr, Qb, 0);
    gemm_bf16<<<gg, 256, 0, stream>>>(xb, Wkb, nullptr, Kb, 0);
    gemm_bf16<<<gg, 256, 0, stream>>>(xb, Wvb, nullptr, Vb, 0);
    gemm_bf16<<<gg, 256, 0, stream>>>(xb, Wlrb, b_lr, LRb, 1);  // fused sigmoid

    l2norm_kq<<<(Bsz * Tlen * Hh) / 4, 256, 0, stream>>>(Kb, Vb, Qb, KQ);

    scan_kernel<<<Bsz * Hh * 32, 64, 0, stream>>>(Qb, Kb, Vb, LRb, KQ, Obb);

    gemm_bf16<<<gg, 256, 0, stream>>>(Obb, Wob, nullptr, (float*)d_out, 0);
}

// Round 6
// 638.705 us; speedup vs baseline: 4.1446x; 1.0672x over previous
//
#include <hip/hip_runtime.h>
#include <math.h>

#define Bsz  4
#define Tlen 2048
#define Dm   1024
#define Hh   8
#define dh   128
#define Mrows (Bsz * Tlen)   // 8192
#define CH   128             // chunk length for pass 2
#define NCH  (Tlen / CH)     // 16 chunks

typedef __attribute__((ext_vector_type(8))) short  s16x8;
typedef __attribute__((ext_vector_type(4))) float  f32x4;

// DPP cross-lane add at VALU latency.
#define DPP_ADD(x, ctrl) \
    ((x) + __int_as_float(__builtin_amdgcn_update_dpp( \
        0, __float_as_int(x), (ctrl), 0xf, 0xf, true)))
// ds_swizzle xor16 (BitMode: xor_mask=16, and_mask=0x1F)
#define SWZ_ADD16(x) \
    ((x) + __int_as_float(__builtin_amdgcn_ds_swizzle(__float_as_int(x), 0x401F)))

__device__ inline unsigned short f2b_rne(float f) {
    unsigned int u = __float_as_uint(f);
    u += 0x7FFFu + ((u >> 16) & 1u);
    return (unsigned short)(u >> 16);
}

__global__ __launch_bounds__(256) void cvt_f32_bf16(const float* __restrict__ in,
                                                    unsigned short* __restrict__ out)
{
    const size_t i = ((size_t)blockIdx.x * 256 + threadIdx.x) * 4;
    float4 v = *(const float4*)&in[i];
    ushort4 o;
    o.x = f2b_rne(v.x); o.y = f2b_rne(v.y);
    o.z = f2b_rne(v.z); o.w = f2b_rne(v.w);
    *(ushort4*)&out[i] = o;
}

// ---------------------------------------------------------------------------
// bf16 MFMA GEMM: val = sum_k A[m][k]*W[n][k] (+bias)
// mode 0: Yf = val;  mode 1: Yf = sigmoid(val);  mode 2: Y16 = bf16(val)
// ---------------------------------------------------------------------------
__global__ __launch_bounds__(256) void gemm_bf16(const unsigned short* __restrict__ A,
                                                 const unsigned short* __restrict__ Wt,
                                                 const float* __restrict__ bias,
                                                 float* __restrict__ Yf,
                                                 unsigned short* __restrict__ Y16,
                                                 int mode)
{
    __shared__ __align__(16) unsigned short As[128 * 32];
    __shared__ __align__(16) unsigned short Bs[128 * 32];

    const int tid   = threadIdx.x;
    const int w     = tid >> 6;
    const int lane  = tid & 63;
    const int r4    = lane >> 2;
    const int p4    = lane & 3;
    const int row16 = lane & 15;
    const int quad  = lane >> 4;

    const int m0 = blockIdx.y * 128;
    const int n0 = blockIdx.x * 128;
    const int wm = (w >> 1) * 64;
    const int wn = (w & 1) * 64;

    f32x4 acc[4][4];
#pragma unroll
    for (int i = 0; i < 4; ++i)
#pragma unroll
        for (int j = 0; j < 4; ++j)
            acc[i][j] = (f32x4){0.f, 0.f, 0.f, 0.f};

    for (int k0 = 0; k0 < 1024; k0 += 32) {
        __syncthreads();
#pragma unroll
        for (int c = 0; c < 2; ++c) {
            const int ml  = w * 32 + c * 16 + r4;
            const int swz = (ml >> 1) & 3;
            const unsigned short* ga = A  + (size_t)(m0 + ml) * 1024 + k0 + ((p4 ^ swz) << 3);
            const unsigned short* gb = Wt + (size_t)(n0 + ml) * 1024 + k0 + ((p4 ^ swz) << 3);
            __builtin_amdgcn_global_load_lds(
                (const __attribute__((address_space(1))) void*)ga,
                (__attribute__((address_space(3))) void*)&As[(w * 32 + c * 16) * 32], 16, 0, 0);
            __builtin_amdgcn_global_load_lds(
                (const __attribute__((address_space(1))) void*)gb,
                (__attribute__((address_space(3))) void*)&Bs[(w * 32 + c * 16) * 32], 16, 0, 0);
        }
        __syncthreads();

        s16x8 af[4], bf[4];
#pragma unroll
        for (int bm = 0; bm < 4; ++bm) {
            const int ml  = wm + bm * 16 + row16;
            const int pos = quad ^ ((ml >> 1) & 3);
            af[bm] = *(const s16x8*)&As[ml * 32 + pos * 8];
        }
#pragma unroll
        for (int bn = 0; bn < 4; ++bn) {
            const int nl  = wn + bn * 16 + row16;
            const int pos = quad ^ ((nl >> 1) & 3);
            bf[bn] = *(const s16x8*)&Bs[nl * 32 + pos * 8];
        }
#pragma unroll
        for (int bm = 0; bm < 4; ++bm)
#pragma unroll
            for (int bn = 0; bn < 4; ++bn)
                acc[bm][bn] = __builtin_amdgcn_mfma_f32_16x16x32_bf16(af[bm], bf[bn], acc[bm][bn], 0, 0, 0);
    }

#pragma unroll
    for (int bm = 0; bm < 4; ++bm) {
        const int row = m0 + wm + bm * 16 + quad * 4;
#pragma unroll
        for (int bn = 0; bn < 4; ++bn) {
            const int col = n0 + wn + bn * 16 + row16;
            const float bb = bias ? bias[col] : 0.f;
#pragma unroll
            for (int r = 0; r < 4; ++r) {
                float val = acc[bm][bn][r] + bb;
                if (mode == 1) val = 1.f / (1.f + __expf(-val));
                if (mode == 2) Y16[(size_t)(row + r) * 1024 + col] = f2b_rne(val);
                else           Yf [(size_t)(row + r) * 1024 + col] = val;
            }
        }
    }
}

// ---------------------------------------------------------------------------
// L2-normalize K,V rows (128) in place; also write normalized K as bf16.
// ---------------------------------------------------------------------------
__global__ __launch_bounds__(256) void l2norm_rows(float* __restrict__ Kb,
                                                   float* __restrict__ Vb,
                                                   unsigned short* __restrict__ K16)
{
    const int gtid = blockIdx.x * 256 + threadIdx.x;
    const int row  = gtid >> 6;
    const int lane = threadIdx.x & 63;
    const size_t base = (size_t)row * dh + lane * 2;

    float2 k2 = *(float2*)&Kb[base];
    float2 v2 = *(float2*)&Vb[base];
    float sk = k2.x * k2.x + k2.y * k2.y;
    float sv = v2.x * v2.x + v2.y * v2.y;
#pragma unroll
    for (int off = 1; off < 64; off <<= 1) {
        sk += __shfl_xor(sk, off);
        sv += __shfl_xor(sv, off);
    }
    const float rk = 1.f / fmaxf(sqrtf(sk), 1e-12f);
    const float rv = 1.f / fmaxf(sqrtf(sv), 1e-12f);
    k2.x *= rk; k2.y *= rk;
    v2.x *= rv; v2.y *= rv;
    *(float2*)&Kb[base] = k2;
    *(float2*)&Vb[base] = v2;
    const unsigned int pk = (unsigned int)f2b_rne(k2.x) |
                            ((unsigned int)f2b_rne(k2.y) << 16);
    ((unsigned int*)K16)[base >> 1] = pk;
}

// ---------------------------------------------------------------------------
// Pass 1: serial coef-only scan.
// Wave = 2 rows x 32 lanes, 4 state cols/lane.  2048 waves (2/SIMD).
// Per step: d1 = w.k (coalesced float4 k load), butterfly (4 DPP + 1 swizzle),
// coef = lr*(v - d1), w += coef*k.  Coefs (U) stored TRANSPOSED [bh, i, t]
// bf16, packed 8-at-a-time (one 16B store per row per 8 steps by lane 0).
// W checkpointed (bf16, row-major [i][j]) at every chunk start.
// ---------------------------------------------------------------------------
__global__ __launch_bounds__(64) void scan_coef(const float* __restrict__ Kb,
                                                const float* __restrict__ Vb,
                                                const float* __restrict__ LR,
                                                unsigned short* __restrict__ Ut,
                                                unsigned short* __restrict__ Wcp)
{
    const int bid = blockIdx.x;            // 0..2047
    const int bh  = bid & 31;              // all 64 blocks of a bh on one XCD
    const int rg  = bid >> 5;              // 0..63
    const int b   = bh >> 3, h = bh & 7;
    const int lane = threadIdx.x;
    const int rl   = lane >> 5;            // 0..1 (row within wave)
    const int c32  = lane & 31;            // col chunk (4 cols)
    const int row  = rg * 2 + rl;          // 0..127

    const size_t base = (size_t)b * Tlen * Dm + (size_t)h * dh;
    const float* kp = Kb + base + c32 * 4;
    const float* vp = Vb + base + row;
    const float* lp = LR + base + row;
    unsigned short* up = Ut + ((size_t)bh * dh + row) * Tlen;

    float w0 = 0.f, w1 = 0.f, w2 = 0.f, w3 = 0.f;

    float4 kr[8];
    float  vv[8], lv[8];
#pragma unroll
    for (int u = 0; u < 8; ++u) {
        const size_t off = (size_t)u * Dm;
        kr[u] = *(const float4*)(kp + off);
        vv[u] = vp[off];
        lv[u] = lp[off];
    }

    float o8[8];

    for (int t = 0; t < Tlen; t += 8) {
        if ((t & (CH - 1)) == 0) {
            // checkpoint W at chunk start (state after t steps)
            const int c = t >> 7;
            uint2 wc;
            wc.x = (unsigned int)f2b_rne(w0) | ((unsigned int)f2b_rne(w1) << 16);
            wc.y = (unsigned int)f2b_rne(w2) | ((unsigned int)f2b_rne(w3) << 16);
            *(uint2*)&Wcp[(((size_t)bh * NCH + c) * dh + row) * dh + c32 * 4] = wc;
        }
#pragma unroll
        for (int u = 0; u < 8; ++u) {
            const int tc = t + u;
            const float4 k4 = kr[u];
            const float vr = vv[u], lrr = lv[u];

            int tn = tc + 8; if (tn >= Tlen) tn = Tlen - 1;
            const size_t offn = (size_t)tn * Dm;
            kr[u] = *(const float4*)(kp + offn);
            vv[u] = vp[offn];
            lv[u] = lp[offn];

            float d1 = fmaf(w1, k4.y, w0 * k4.x) + fmaf(w3, k4.w, w2 * k4.z);
            d1 = DPP_ADD(d1, 0xB1);    // xor1
            d1 = DPP_ADD(d1, 0x4E);    // xor2
            d1 = DPP_ADD(d1, 0x141);   // xor4 (half-mirror)
            d1 = DPP_ADD(d1, 0x140);   // xor8 (row-mirror)
            d1 = SWZ_ADD16(d1);        // xor16 -> all 32 lanes of the row

            const float coef = lrr * (vr - d1);
            w0 = fmaf(coef, k4.x, w0); w1 = fmaf(coef, k4.y, w1);
            w2 = fmaf(coef, k4.z, w2); w3 = fmaf(coef, k4.w, w3);
            o8[u] = coef;
        }
        // coef is row-uniform: lane 0 of each row packs 8 bf16 -> one 16B store
        uint4 pk;
        pk.x = (unsigned int)f2b_rne(o8[0]) | ((unsigned int)f2b_rne(o8[1]) << 16);
        pk.y = (unsigned int)f2b_rne(o8[2]) | ((unsigned int)f2b_rne(o8[3]) << 16);
        pk.z = (unsigned int)f2b_rne(o8[4]) | ((unsigned int)f2b_rne(o8[5]) << 16);
        pk.w = (unsigned int)f2b_rne(o8[6]) | ((unsigned int)f2b_rne(o8[7]) << 16);
        if (c32 == 0)
            *(uint4*)&up[t] = pk;
    }
}

// ---------------------------------------------------------------------------
// Pass 2: per 128-chunk output via MFMA.
//   S = mask_{s<=t}(Q_c K_c^T)  (bf16 in LDS, +8 pad)
//   O = S @ U_c + Q_c @ Wcp^T   -> Obb (bf16, [b,t,h,i])
// Grid: B*H*NCH = 512 blocks, 256 threads.
// ---------------------------------------------------------------------------
__global__ __launch_bounds__(256) void chunk_o(const unsigned short* __restrict__ Q16,
                                               const unsigned short* __restrict__ K16,
                                               const unsigned short* __restrict__ Ut,
                                               const unsigned short* __restrict__ Wcp,
                                               unsigned short* __restrict__ Obb)
{
    __shared__ __align__(16) unsigned short As[128 * 32];
    __shared__ __align__(16) unsigned short Bs[128 * 32];
    __shared__ __align__(16) unsigned short Sb[128 * 136];   // +8 pad

    const int blk = blockIdx.x;
    const int c   = blk & (NCH - 1);
    const int bh  = blk >> 4;
    const int b   = bh >> 3, h = bh & 7;

    const int tid   = threadIdx.x;
    const int w     = tid >> 6;
    const int lane  = tid & 63;
    const int r4    = lane >> 2;
    const int p4    = lane & 3;
    const int row16 = lane & 15;
    const int quad  = lane >> 4;
    const int wm = (w >> 1) * 64;
    const int wn = (w & 1) * 64;

    // rows t (and s) of this chunk: Q16/K16 + qkbase + t*Dm
    const size_t qkbase = (size_t)b * Tlen * Dm + (size_t)(c * CH) * Dm + (size_t)h * dh;
    const size_t ubase  = (size_t)bh * dh * Tlen + (size_t)c * CH;       // + i*Tlen + s
    const size_t wbase  = ((size_t)bh * NCH + c) * dh * dh;              // + i*dh + j

    f32x4 acc[4][4];
#pragma unroll
    for (int i = 0; i < 4; ++i)
#pragma unroll
        for (int j = 0; j < 4; ++j)
            acc[i][j] = (f32x4){0.f, 0.f, 0.f, 0.f};

    // ---- Stage 1: S = Q K^T  (inner j = 0..127)
    for (int k0 = 0; k0 < 128; k0 += 32) {
        __syncthreads();
#pragma unroll
        for (int cc = 0; cc < 2; ++cc) {
            const int ml  = w * 32 + cc * 16 + r4;
            const int swz = (ml >> 1) & 3;
            const unsigned short* ga = Q16 + qkbase + (size_t)ml * Dm + k0 + ((p4 ^ swz) << 3);
            const unsigned short* gb = K16 + qkbase + (size_t)ml * Dm + k0 + ((p4 ^ swz) << 3);
            __builtin_amdgcn_global_load_lds(
                (const __attribute__((address_space(1))) void*)ga,
                (__attribute__((address_space(3))) void*)&As[(w * 32 + cc * 16) * 32], 16, 0, 0);
            __builtin_amdgcn_global_load_lds(
                (const __attribute__((address_space(1))) void*)gb,
                (__attribute__((address_space(3))) void*)&Bs[(w * 32 + cc * 16) * 32], 16, 0, 0);
        }
        __syncthreads();

        s16x8 af[4], bf[4];
#pragma unroll
        for (int bm = 0; bm < 4; ++bm) {
            const int ml  = wm + bm * 16 + row16;
            const int pos = quad ^ ((ml >> 1) & 3);
            af[bm] = *(const s16x8*)&As[ml * 32 + pos * 8];
        }
#pragma unroll
        for (int bn = 0; bn < 4; ++bn) {
            const int nl  = wn + bn * 16 + row16;
            const int pos = quad ^ ((nl >> 1) & 3);
            bf[bn] = *(const s16x8*)&Bs[nl * 32 + pos * 8];
        }
#pragma unroll
        for (int bm = 0; bm < 4; ++bm)
#pragma unroll
            for (int bn = 0; bn < 4; ++bn)
                acc[bm][bn] = __builtin_amdgcn_mfma_f32_16x16x32_bf16(af[bm], bf[bn], acc[bm][bn], 0, 0, 0);
    }

    // mask (s <= t), convert, write to Sb; reset acc
#pragma unroll
    for (int bm = 0; bm < 4; ++bm) {
#pragma unroll
        for (int bn = 0; bn < 4; ++bn) {
            const int s_loc = wn + bn * 16 + row16;
#pragma unroll
            for (int r = 0; r < 4; ++r) {
                const int t_loc = wm + bm * 16 + quad * 4 + r;
                const float val = (s_loc <= t_loc) ? acc[bm][bn][r] : 0.f;
                Sb[t_loc * 136 + s_loc] = f2b_rne(val);
            }
            acc[bm][bn] = (f32x4){0.f, 0.f, 0.f, 0.f};
        }
    }

    // ---- Stage 2a: O += S @ U  (inner s = 0..127; A from Sb, B from Ut rows i)
    for (int k0 = 0; k0 < 128; k0 += 32) {
        __syncthreads();
#pragma unroll
        for (int cc = 0; cc < 2; ++cc) {
            const int nl  = w * 32 + cc * 16 + r4;
            const int swz = (nl >> 1) & 3;
            const unsigned short* gb = Ut + ubase + (size_t)nl * Tlen + k0 + ((p4 ^ swz) << 3);
            __builtin_amdgcn_global_load_lds(
                (const __attribute__((address_space(1))) void*)gb,
                (__attribute__((address_space(3))) void*)&Bs[(w * 32 + cc * 16) * 32], 16, 0, 0);
        }
        __syncthreads();

        s16x8 af[4], bf[4];
#pragma unroll
        for (int bm = 0; bm < 4; ++bm) {
            const int ml = wm + bm * 16 + row16;
            af[bm] = *(const s16x8*)&Sb[ml * 136 + k0 + quad * 8];
        }
#pragma unroll
        for (int bn = 0; bn < 4; ++bn) {
            const int nl  = wn + bn * 16 + row16;
            const int pos = quad ^ ((nl >> 1) & 3);
            bf[bn] = *(const s16x8*)&Bs[nl * 32 + pos * 8];
        }
#pragma unroll
        for (int bm = 0; bm < 4; ++bm)
#pragma unroll
            for (int bn = 0; bn < 4; ++bn)
                acc[bm][bn] = __builtin_amdgcn_mfma_f32_16x16x32_bf16(af[bm], bf[bn], acc[bm][bn], 0, 0, 0);
    }

    // ---- Stage 2b: O += Q @ Wcp^T  (inner j = 0..127)
    for (int k0 = 0; k0 < 128; k0 += 32) {
        __syncthreads();
#pragma unroll
        for (int cc = 0; cc < 2; ++cc) {
            const int ml  = w * 32 + cc * 16 + r4;
            const int swz = (ml >> 1) & 3;
            const unsigned short* ga = Q16 + qkbase + (size_t)ml * Dm + k0 + ((p4 ^ swz) << 3);
            const unsigned short* gb = Wcp + wbase + (size_t)ml * dh + k0 + ((p4 ^ swz) << 3);
            __builtin_amdgcn_global_load_lds(
                (const __attribute__((address_space(1))) void*)ga,
                (__attribute__((address_space(3))) void*)&As[(w * 32 + cc * 16) * 32], 16, 0, 0);
            __builtin_amdgcn_global_load_lds(
                (const __attribute__((address_space(1))) void*)gb,
                (__attribute__((address_space(3))) void*)&Bs[(w * 32 + cc * 16) * 32], 16, 0, 0);
        }
        __syncthreads();

        s16x8 af[4], bf[4];
#pragma unroll
        for (int bm = 0; bm < 4; ++bm) {
            const int ml  = wm + bm * 16 + row16;
            const int pos = quad ^ ((ml >> 1) & 3);
            af[bm] = *(const s16x8*)&As[ml * 32 + pos * 8];
        }
#pragma unroll
        for (int bn = 0; bn < 4; ++bn) {
            const int nl  = wn + bn * 16 + row16;
            const int pos = quad ^ ((nl >> 1) & 3);
            bf[bn] = *(const s16x8*)&Bs[nl * 32 + pos * 8];
        }
#pragma unroll
        for (int bm = 0; bm < 4; ++bm)
#pragma unroll
            for (int bn = 0; bn < 4; ++bn)
                acc[bm][bn] = __builtin_amdgcn_mfma_f32_16x16x32_bf16(af[bm], bf[bn], acc[bm][bn], 0, 0, 0);
    }

    // epilogue: Obb[b, c*128 + t_loc, h, i_loc] bf16
#pragma unroll
    for (int bm = 0; bm < 4; ++bm) {
#pragma unroll
        for (int bn = 0; bn < 4; ++bn) {
            const int i_loc = wn + bn * 16 + row16;
#pragma unroll
            for (int r = 0; r < 4; ++r) {
                const int t_loc = wm + bm * 16 + quad * 4 + r;
                Obb[qkbase + (size_t)t_loc * Dm + i_loc] = f2b_rne(acc[bm][bn][r]);
            }
        }
    }
}

// ---------------------------------------------------------------------------
extern "C" void kernel_launch(void* const* d_in, const int* in_sizes, int n_in,
                              void* d_out, int out_size, void* d_ws, size_t ws_size,
                              hipStream_t stream)
{
    const float* x    = (const float*)d_in[0];
    const float* Wq   = (const float*)d_in[1];
    const float* Wk   = (const float*)d_in[2];
    const float* Wv   = (const float*)d_in[3];
    const float* Wo   = (const float*)d_in[4];
    const float* Wlr  = (const float*)d_in[5];
    const float* b_lr = (const float*)d_in[6];

    float* ws = (float*)d_ws;
    const size_t S  = (size_t)Mrows * Dm;    // 8388608
    const size_t SW = (size_t)Dm * Dm;       // 1048576
    float* Kb  = ws;
    float* Vb  = ws + S;
    float* LRb = ws + 2 * S;
    unsigned short* xb   = (unsigned short*)(ws + 3 * S);  // S bf16
    unsigned short* Wcp  = xb;                             // alias: xb dead before pass 1
    unsigned short* Q16  = xb + S;
    unsigned short* K16  = Q16 + S;
    unsigned short* Ut   = K16 + S;                        // S bf16 (= B*H*dh*T)
    unsigned short* Obb  = Ut + S;
    unsigned short* Wqb  = Obb + S;
    unsigned short* Wkb  = Wqb + SW;
    unsigned short* Wvb  = Wkb + SW;
    unsigned short* Wlrb = Wvb + SW;
    unsigned short* Wob  = Wlrb + SW;

    cvt_f32_bf16<<<S / 1024, 256, 0, stream>>>(x, xb);
    cvt_f32_bf16<<<SW / 1024, 256, 0, stream>>>(Wq, Wqb);
    cvt_f32_bf16<<<SW / 1024, 256, 0, stream>>>(Wk, Wkb);
    cvt_f32_bf16<<<SW / 1024, 256, 0, stream>>>(Wv, Wvb);
    cvt_f32_bf16<<<SW / 1024, 256, 0, stream>>>(Wlr, Wlrb);
    cvt_f32_bf16<<<SW / 1024, 256, 0, stream>>>(Wo, Wob);

    dim3 gg(Dm / 128, Mrows / 128);   // (8, 64)
    gemm_bf16<<<gg, 256, 0, stream>>>(xb, Wqb, nullptr, nullptr, Q16, 2);  // Q -> bf16 only
    gemm_bf16<<<gg, 256, 0, stream>>>(xb, Wkb, nullptr, Kb, nullptr, 0);
    gemm_bf16<<<gg, 256, 0, stream>>>(xb, Wvb, nullptr, Vb, nullptr, 0);
    gemm_bf16<<<gg, 256, 0, stream>>>(xb, Wlrb, b_lr, LRb, nullptr, 1);    // fused sigmoid

    l2norm_rows<<<(Bsz * Tlen * Hh) / 4, 256, 0, stream>>>(Kb, Vb, K16);

    scan_coef<<<Bsz * Hh * 64, 64, 0, stream>>>(Kb, Vb, LRb, Ut, Wcp);

    chunk_o<<<Bsz * Hh * NCH, 256, 0, stream>>>(Q16, K16, Ut, Wcp, Obb);

    gemm_bf16<<<gg, 256, 0, stream>>>(Obb, Wob, nullptr, (float*)d_out, nullptr, 0);
}